// Round 6
// baseline (136.687 us; speedup 1.0000x reference)
//
#include <hip/hip_runtime.h>
#include <hip/hip_bf16.h>

// JPEG 8x8 block DCT + quantization.
// image: [16,1,1024,1024] fp32; quality_factor: [16] fp32
// out:   [16,64,128,128] fp32, channel = k*8+l, out = (C @ (blk-128) @ C^T) / (factor*Q)
//
// R6: per-INSTRUCTION 1KB memory granularity on both sides. R2-R5 (granules
// 4B..256B scattered across planes) all pinned at ~40us / 2.4TB/s despite ample
// MLP+occupancy+issue headroom => memory-system pattern limit. The d2d copy that
// hits 6.3TB/s uses 1KB contiguous per wave instr. Here:
//  - loads: lane-consecutive float4 -> 1KB/wave-load, full 4KB rows per WG
//  - stage B transpose via one __shfl_xor(1) partial exchange (no LDS, no barrier)
//  - flush: each wave-store = 64 lanes x 16B = 1KB contiguous in ONE plane
// WG=512 thr = (b, h-pair, all 128 w) = 256 blocks, 2 thr/block (4 cols each).
// ldsB 64KB -> 2 WGs/CU resident, 32 waves/CU supply, 1 barrier total.

#define BS 8
#define HPIX 1024
#define WPIX 1024
#define HB (HPIX / BS)   // 128
#define WB (WPIX / BS)   // 128
#define BATCH 16

// Orthonormal DCT-II matrix C[k][n] = f_k * cos(pi*(2n+1)*k/16), fp32-rounded.
constexpr float DCT[8][8] = {
  { 0.35355339059327373f,  0.35355339059327373f,  0.35355339059327373f,  0.35355339059327373f,
    0.35355339059327373f,  0.35355339059327373f,  0.35355339059327373f,  0.35355339059327373f },
  { 0.49039264020161522f,  0.41573480615127262f,  0.27778511650980114f,  0.09754516100806413f,
   -0.09754516100806413f, -0.27778511650980114f, -0.41573480615127262f, -0.49039264020161522f },
  { 0.46193976625564337f,  0.19134171618254492f, -0.19134171618254492f, -0.46193976625564337f,
   -0.46193976625564337f, -0.19134171618254492f,  0.19134171618254492f,  0.46193976625564337f },
  { 0.41573480615127262f, -0.09754516100806413f, -0.49039264020161522f, -0.27778511650980114f,
    0.27778511650980114f,  0.49039264020161522f,  0.09754516100806413f, -0.41573480615127262f },
  { 0.35355339059327373f, -0.35355339059327373f, -0.35355339059327373f,  0.35355339059327373f,
    0.35355339059327373f, -0.35355339059327373f, -0.35355339059327373f,  0.35355339059327373f },
  { 0.27778511650980114f, -0.49039264020161522f,  0.09754516100806413f,  0.41573480615127262f,
   -0.41573480615127262f, -0.09754516100806413f,  0.49039264020161522f, -0.27778511650980114f },
  { 0.19134171618254492f, -0.46193976625564337f,  0.46193976625564337f, -0.19134171618254492f,
   -0.19134171618254492f,  0.46193976625564337f, -0.46193976625564337f,  0.19134171618254492f },
  { 0.09754516100806413f, -0.27778511650980114f,  0.41573480615127262f, -0.49039264020161522f,
    0.49039264020161522f, -0.41573480615127262f,  0.27778511650980114f, -0.09754516100806413f },
};

// 1 / (LUMINANCE_QUANTIZATION_TABLE / 100) = 100 / table entry
constexpr float INVQ[8][8] = {
  { 6.25f,              9.09090909090909f,  10.0f,              6.25f,
    4.16666666666667f,  2.5f,               1.96078431372549f,  1.63934426229508f },
  { 8.33333333333333f,  8.33333333333333f,  7.14285714285714f,  5.26315789473684f,
    3.84615384615385f,  1.72413793103448f,  1.66666666666667f,  1.81818181818182f },
  { 7.14285714285714f,  7.69230769230769f,  6.25f,              4.16666666666667f,
    2.5f,               1.75438596491228f,  1.44927536231884f,  1.78571428571429f },
  { 7.14285714285714f,  5.88235294117647f,  4.54545454545455f,  3.44827586206897f,
    1.96078431372549f,  1.14942528735632f,  1.25f,              1.61290322580645f },
  { 5.55555555555556f,  4.54545454545455f,  2.70270270270270f,  1.78571428571429f,
    1.47058823529412f,  0.91743119266055f,  0.970873786407767f, 1.29870129870130f },
  { 4.16666666666667f,  2.77777777777778f,  1.81818181818182f,  1.5625f,
    1.23456790123457f,  0.961538461538462f, 0.884955752212389f, 1.08695652173913f },
  { 2.04081632653061f,  1.5625f,            1.28205128205128f,  1.14942528735632f,
    0.970873786407767f, 0.826446280991736f, 0.833333333333333f, 0.990099009900990f },
  { 1.38888888888889f,  1.08695652173913f,  1.05263157894737f,  1.02040816326531f,
    0.892857142857143f, 1.0f,               0.970873786407767f, 1.01010101010101f },
};

__global__ __launch_bounds__(512, 4) void jpeg_dct_q_kernel(
    const float* __restrict__ img,
    const float* __restrict__ qf,
    float* __restrict__ out)
{
    // Final results staged per (ch, pos): pos = hs*128 + w covers the 2 plane
    // rows h0,h0+1 = 256 consecutive floats = 1 KB per ch. 64 KB total.
    __shared__ float ldsB[64][256];

    const int t  = threadIdx.x;
    const int wg = blockIdx.x;
    const int b  = wg >> 6;                 // batch (uniform)
    const int h0 = (wg & 63) << 1;          // block-row pair base (uniform)
    const int blk  = t >> 1;                // block 0..255 within WG
    const int half = t & 1;                 // which 4 columns of the block
    const int hs = blk >> 7;                // 0/1: which block-row of the pair
    const int w  = blk & 127;               // block col

    // Loads: addr = w*8 + half*4 = t*4 floats -> lane-consecutive float4:
    // each wave-load = 64 x 16B = 1 KB contiguous. 8 rows at 4 KB stride.
    const float* base = img + ((size_t)b << 20)
                            + (size_t)((h0 + hs) * BS) * WPIX
                            + (size_t)(w * BS + half * 4);
    float4 pix[8];
#pragma unroll
    for (int n = 0; n < 8; ++n)
        pix[n] = *reinterpret_cast<const float4*>(base + (size_t)n * WPIX);

    // Stage A: T[k][j] = sum_n DCT[k][n] * pix[n][j]  (j = local col 0..3).
    // -128 folds into DC only: T[0][j] -= 1024*C[0][0].
    float T[8][4];
#pragma unroll
    for (int k = 0; k < 8; ++k)
#pragma unroll
        for (int j = 0; j < 4; ++j)
            T[k][j] = 0.0f;
#pragma unroll
    for (int n = 0; n < 8; ++n) {
        const float* pr = reinterpret_cast<const float*>(&pix[n]);
        float r0 = pr[0], r1 = pr[1], r2 = pr[2], r3 = pr[3];
#pragma unroll
        for (int k = 0; k < 8; ++k) {
            const float cf = DCT[k][n];
            T[k][0] = fmaf(cf, r0, T[k][0]);
            T[k][1] = fmaf(cf, r1, T[k][1]);
            T[k][2] = fmaf(cf, r2, T[k][2]);
            T[k][3] = fmaf(cf, r3, T[k][3]);
        }
    }
#pragma unroll
    for (int j = 0; j < 4; ++j)
        T[0][j] -= 362.03867196751236f;   // 1024 * 0.35355339059327373

    // Partial-sum coefficients: cf[l][j] = DCT[l][half*4 + j] (select on half).
    float cf[8][4];
#pragma unroll
    for (int l = 0; l < 8; ++l)
#pragma unroll
        for (int j = 0; j < 4; ++j)
            cf[l][j] = half ? DCT[l][4 + j] : DCT[l][j];

    // Quantization scale: factor = QF<50 ? 5000/QF : 200-2*QF  (uniform per WG)
    const float q = qf[b];
    const float factor = (q < 50.0f) ? (5000.0f / q) : (200.0f - 2.0f * q);
    const float rf = 1.0f / factor;

    // Stage B: per k, partial p[l] over own 4 columns; full sum via one
    // shfl_xor(1) with the sibling thread (other 4 columns of the same block).
    // Thread writes channels l = half*4 + i. ldsB bank: addr%32 = blk%32 and the
    // two halves of a lane-pair hit the same bank -> 2-way = free.
#pragma unroll
    for (int k = 0; k < 8; ++k) {
        float p[8];
#pragma unroll
        for (int l = 0; l < 8; ++l) {
            float s = 0.0f;
#pragma unroll
            for (int j = 0; j < 4; ++j)
                s = fmaf(cf[l][j], T[k][j], s);
            p[l] = s;
        }
        float fs[8];
#pragma unroll
        for (int l = 0; l < 8; ++l)
            fs[l] = p[l] + __shfl_xor(p[l], 1, 64);
#pragma unroll
        for (int i = 0; i < 4; ++i) {
            const float v  = half ? fs[4 + i] : fs[i];
            const float iq = half ? INVQ[k][4 + i] : INVQ[k][i];
            const int ch = k * 8 + half * 4 + i;
            ldsB[ch][blk] = v * rf * iq;
        }
    }
    __syncthreads();

    // Flush: wave wv owns channels wv*8..wv*8+7. Each instr: 64 lanes x 16B
    // = 1 KB contiguous in ONE plane (rows h0,h0+1). LDS read phases are
    // conflict-free (8 lanes span all 32 banks exactly once).
    const int lane = t & 63;
    const int wv   = t >> 6;
    float* outbase = out + ((size_t)b << 20) + (size_t)(h0 * WB) + (size_t)(lane * 4);
#pragma unroll
    for (int s = 0; s < 8; ++s) {
        const int ch = wv * 8 + s;
        const float4 v = *reinterpret_cast<const float4*>(&ldsB[ch][lane * 4]);
        *reinterpret_cast<float4*>(outbase + (size_t)ch * (HB * WB)) = v;
    }
}

extern "C" void kernel_launch(void* const* d_in, const int* in_sizes, int n_in,
                              void* d_out, int out_size, void* d_ws, size_t ws_size,
                              hipStream_t stream) {
    const float* img = (const float*)d_in[0];
    const float* qf  = (const float*)d_in[1];
    float* out = (float*)d_out;

    const int grid = BATCH * (HB / 2);   // 1024 WGs: one per (batch, block-row pair)
    const int block = 512;

    jpeg_dct_q_kernel<<<grid, block, 0, stream>>>(img, qf, out);
}